// Round 4
// baseline (291.973 us; speedup 1.0000x reference)
//
#include <hip/hip_runtime.h>
#include <stdint.h>

typedef unsigned short ushort_t;
typedef __attribute__((ext_vector_type(8))) __bf16 bf16x8;
typedef __attribute__((ext_vector_type(4))) float  f32x4;

// ---------- helpers ----------

__device__ __forceinline__ unsigned int f2bf(float f) {
    unsigned int u = __float_as_uint(f);
    return (u + 0x7FFFu + ((u >> 16) & 1u)) >> 16;  // RNE
}
__device__ __forceinline__ unsigned int pk2bf(float lo, float hi) {
    return f2bf(lo) | (f2bf(hi) << 16);
}

// Cayley sign for e_a * e_b in Cl(4,1), SIG = [1,1,1,1,-1]
__device__ __forceinline__ float cayley_sign(int a, int b) {
    int s = 0;
    int aa = a >> 1;
    while (aa) { s += __popc(aa & b); aa >>= 1; }
    float sign = (s & 1) ? -1.0f : 1.0f;
    if (a & b & 16) sign = -sign;   // only SIG[4] = -1
    return sign;
}

// async global->LDS, 16 bytes per lane. LDS dest is wave-uniform base + lane*16.
__device__ __forceinline__ void async16(const ushort_t* g, const ushort_t* l) {
    const __attribute__((address_space(1))) unsigned int* gp =
        (const __attribute__((address_space(1))) unsigned int*)(uintptr_t)g;
    __attribute__((address_space(3))) unsigned int* lp =
        (__attribute__((address_space(3))) unsigned int*)(unsigned int)(uintptr_t)l;
    __builtin_amdgcn_global_load_lds(gp, lp, 16, 0, 0);
}

// ---------- B prep kernel (Cayley-folded weight, swizzled bf16 image) ----------
// B image per (panel P of 256 cols, k-tile kt of 64): 16384 bf16 laid out
// [k8(8)][col(256)][j(8)], k = k8*8+j. Each 16 KiB half = one staging half-tile.
__global__ __launch_bounds__(256) void prepB(const float* __restrict__ w,
                                             ushort_t* __restrict__ B_sw) {
    const int k_blk = blockIdx.x;            // 0..127 (32-k chunk)
    const int p_blk = blockIdx.y >> 1;       // 0..31 (128-col panel)
    const int sub   = blockIdx.y & 1;        // 0..1
    const int t = threadIdx.x;               // 0..255
    const int r  = sub * 64 + (t >> 2);      // 0..127 col within 128-panel
    const int kq = t & 3;                    // 0..3

    const int kt = k_blk >> 1;               // 64-k tile index
    const int kh = k_blk & 1;                // 32-k half

    const int n = p_blk * 128 + r;
    const int o = n >> 5;
    const int kc = n & 31;
    const float* wrow = w + (size_t)o * 4096 + (size_t)k_blk * 32;
    unsigned int pk[4];
#pragma unroll
    for (int pr = 0; pr < 4; ++pr) {
        const int i0 = kq * 8 + pr * 2, i1 = i0 + 1;
        const int j0 = i0 ^ kc, j1 = i1 ^ kc;
        float v0 = wrow[j0] * cayley_sign(i0, j0);
        float v1 = wrow[j1] * cayley_sign(i1, j1);
        pk[pr] = f2bf(v0) | (f2bf(v1) << 16);
    }
    uint4 u = {pk[0], pk[1], pk[2], pk[3]};
    const int P = n >> 8, colp = n & 255;
    *(uint4*)(B_sw + (size_t)(P * 64 + kt) * 16384 + kh * 8192 + kq * 2048 + colp * 8) = u;
}

// ---------- GEMM: 256x256, BK=64, 8 waves, fused A-staging from x ----------
// A is staged straight from f32 x: per staging phase each wave loads 16 f32
// (coalesced 128-B lines), converts RNE to bf16, ds_write_b128 into the SAME
// LDS image/slots the old global_load_lds path used (hazard proofs unchanged):
//   ph0(t): write A(t+1)h1 -> As[b^1]h1 (regP, loaded ph2(t-1)); issue regQ=A(t+2)h0
//   ph2(t): write A(t+2)h0 -> As[b]h0   (regQ, loaded ph0(t));   issue regP=A(t+2)h1
// B staging via global_load_lds from B_sw at ph1/ph3 (unchanged).
// Compiler's dataflow vmcnt before each convert (=2 newer B-ops) also drains all
// older B gloads before their ds_reads; barriers publish cross-wave.

#define MFMA16(a, b, c) __builtin_amdgcn_mfma_f32_16x16x32_bf16(a, b, c, 0, 0, 0)

#define RD_A4(d0, d1, d2, d3, base, KH, TMB) do {                              \
        const ushort_t* _p = (base) + aOff + (KH) * 8192 + (TMB) * 128;        \
        d0 = *(const bf16x8*)(_p + 0 * 128);                                   \
        d1 = *(const bf16x8*)(_p + 1 * 128);                                   \
        d2 = *(const bf16x8*)(_p + 2 * 128);                                   \
        d3 = *(const bf16x8*)(_p + 3 * 128);                                   \
    } while (0)

#define RD_B4(d0, d1, d2, d3, base, KH) do {                                   \
        const ushort_t* _p = (base) + bOff + (KH) * 8192;                      \
        d0 = *(const bf16x8*)(_p + 0 * 128);                                   \
        d1 = *(const bf16x8*)(_p + 1 * 128);                                   \
        d2 = *(const bf16x8*)(_p + 2 * 128);                                   \
        d3 = *(const bf16x8*)(_p + 3 * 128);                                   \
    } while (0)

// load 16 f32 of A-tile T, half H (2 rows x 32 B, coalesced 128-B lines)
#define A_ISSUE(S0, S1, S2, S3, T, H) do {                                     \
        const float* _s = xbase + (size_t)(T) * 64 + (H) * 32;                 \
        S0 = *(const float4*)_s;           S1 = *(const float4*)(_s + 4);      \
        S2 = *(const float4*)(_s + 65536); S3 = *(const float4*)(_s + 65536 + 4); \
    } while (0)

// convert + ds_write into As[BUF] half H at this lane's image slot
#define A_WRITE(S0, S1, S2, S3, BUF, H) do {                                   \
        uint4 _p0, _p1;                                                        \
        _p0.x = pk2bf(S0.x, S0.y); _p0.y = pk2bf(S0.z, S0.w);                  \
        _p0.z = pk2bf(S1.x, S1.y); _p0.w = pk2bf(S1.z, S1.w);                  \
        _p1.x = pk2bf(S2.x, S2.y); _p1.y = pk2bf(S2.z, S2.w);                  \
        _p1.z = pk2bf(S3.x, S3.y); _p1.w = pk2bf(S3.z, S3.w);                  \
        ushort_t* _d = &As[BUF][(H) * 8192 + awOff];                           \
        *(uint4*)_d = _p0; *(uint4*)(_d + 128) = _p1;                          \
    } while (0)

#define PHASE(STAGE_STMT, RD_STMT, TMB, A0, A1, A2, A3, TAIL)                  \
    {                                                                          \
        STAGE_STMT;                                                            \
        RD_STMT;                                                               \
        __builtin_amdgcn_sched_barrier(0);                                     \
        __builtin_amdgcn_s_setprio(1);                                         \
        acc[(TMB) + 0][0] = MFMA16(A0, B0_, acc[(TMB) + 0][0]);                \
        acc[(TMB) + 0][1] = MFMA16(A0, B1_, acc[(TMB) + 0][1]);                \
        acc[(TMB) + 0][2] = MFMA16(A0, B2_, acc[(TMB) + 0][2]);                \
        acc[(TMB) + 0][3] = MFMA16(A0, B3_, acc[(TMB) + 0][3]);                \
        acc[(TMB) + 1][0] = MFMA16(A1, B0_, acc[(TMB) + 1][0]);                \
        acc[(TMB) + 1][1] = MFMA16(A1, B1_, acc[(TMB) + 1][1]);                \
        acc[(TMB) + 1][2] = MFMA16(A1, B2_, acc[(TMB) + 1][2]);                \
        acc[(TMB) + 1][3] = MFMA16(A1, B3_, acc[(TMB) + 1][3]);                \
        acc[(TMB) + 2][0] = MFMA16(A2, B0_, acc[(TMB) + 2][0]);                \
        acc[(TMB) + 2][1] = MFMA16(A2, B1_, acc[(TMB) + 2][1]);                \
        acc[(TMB) + 2][2] = MFMA16(A2, B2_, acc[(TMB) + 2][2]);                \
        acc[(TMB) + 2][3] = MFMA16(A2, B3_, acc[(TMB) + 2][3]);                \
        acc[(TMB) + 3][0] = MFMA16(A3, B0_, acc[(TMB) + 3][0]);                \
        acc[(TMB) + 3][1] = MFMA16(A3, B1_, acc[(TMB) + 3][1]);                \
        acc[(TMB) + 3][2] = MFMA16(A3, B2_, acc[(TMB) + 3][2]);                \
        acc[(TMB) + 3][3] = MFMA16(A3, B3_, acc[(TMB) + 3][3]);                \
        __builtin_amdgcn_s_setprio(0);                                         \
        TAIL;                                                                  \
        __builtin_amdgcn_s_barrier();                                          \
    }

__global__ __launch_bounds__(512, 2) void gemm_norm(const float* __restrict__ x,
                                                    const ushort_t* __restrict__ B_sw,
                                                    float* __restrict__ out) {
    __shared__ ushort_t As[2][16384];   // 2 x 32 KiB
    __shared__ ushort_t Bs[2][16384];   // 2 x 32 KiB  (128 KiB total, 1 block/CU)

    // XCD-aware bijective swizzle over the 256-block grid (256 % 8 == 0)
    int id = blockIdx.x;
    id = (id & 7) * 32 + (id >> 3);
    const int m_blk = id >> 4;          // 0..15
    const int n_blk = id & 15;          // 0..15

    const int t    = threadIdx.x;
    const int wave = t >> 6;            // 0..7
    const int lane = t & 63;
    const int wr = wave >> 2;           // 0..1
    const int wc = wave & 3;            // 0..3
    const int lg = lane >> 4;           // 0..3
    const int lm = lane & 15;           // 0..15

    const int aOff = (lg * 256 + wr * 128 + lm) * 8;   // frag-read offset, A image
    const int bOff = (lg * 256 + wc * 64  + lm) * 8;   // frag-read offset, B image
    // A-staging write slot: k8 = lane&3, row = wave*32 + (lane>>2) (+16 for 2nd write)
    const int awOff = (lane & 3) * 2048 + (wave * 32 + (lane >> 2)) * 8;

    // per-lane global base: row m_blk*256 + wave*32 + (lane>>2), col (lane&3)*8
    const float* xbase = x + (size_t)(m_blk * 256 + wave * 32 + (lane >> 2)) * 4096
                           + (lane & 3) * 8;
    const ushort_t* bPanel = B_sw + (size_t)n_blk * 64 * 16384;

    f32x4 acc[8][4];
#pragma unroll
    for (int i = 0; i < 8; ++i)
#pragma unroll
        for (int j = 0; j < 4; ++j)
#pragma unroll
            for (int k = 0; k < 4; ++k) acc[i][j][k] = 0.0f;

    const int so = wave * 1024 + lane * 8;
    const int sl = wave * 1024;
    auto STAGE2B = [&](const ushort_t* src, ushort_t* ldsb) {
        async16(src + so,       ldsb + sl);
        async16(src + so + 512, ldsb + sl + 512);
    };

    const int NT = 64;
    float4 P0, P1, P2, P3, Q0, Q1, Q2, Q3;

    // ---- prologue ----
    // B gloads first: B0h0, B0h1, B1h0, B1h1 (8 vm-ops)
    STAGE2B(bPanel + 0,             &Bs[0][0]);
    STAGE2B(bPanel + 8192,          &Bs[0][8192]);
    STAGE2B(bPanel + 16384,         &Bs[1][0]);
    STAGE2B(bPanel + 16384 + 8192,  &Bs[1][8192]);
    // A(0)h0, A(0)h1, A(1)h0 staged; regP = A(1)h1 left in flight
    A_ISSUE(Q0, Q1, Q2, Q3, 0, 0);
    A_ISSUE(P0, P1, P2, P3, 0, 1);
    A_WRITE(Q0, Q1, Q2, Q3, 0, 0);   // compiler auto-vmcnt drains B gloads too
    A_WRITE(P0, P1, P2, P3, 0, 1);
    A_ISSUE(Q0, Q1, Q2, Q3, 1, 0);
    A_WRITE(Q0, Q1, Q2, Q3, 1, 0);
    A_ISSUE(P0, P1, P2, P3, 1, 1);   // regP in flight into the loop
    asm volatile("s_waitcnt vmcnt(4) lgkmcnt(0)" ::: "memory");
    __builtin_amdgcn_s_barrier();

    // fragment register sets (ping-pong)
    bf16x8 aX0, aX1, aX2, aX3, aY0, aY1, aY2, aY3;
    bf16x8 bX0, bX1, bX2, bX3, bY0, bY1, bY2, bY3;

    RD_A4(aX0, aX1, aX2, aX3, &As[0][0], 0, 0);
    RD_B4(bX0, bX1, bX2, bX3, &Bs[0][0], 0);

#define B0_ bX0
#define B1_ bX1
#define B2_ bX2
#define B3_ bX3

#pragma unroll 2
    for (int tt = 0; tt < NT - 2; ++tt) {
        const int b = tt & 1;
        const ushort_t* Ac = &As[b][0];
        const ushort_t* Bc = &Bs[b][0];
        const ushort_t* An = &As[b ^ 1][0];
        const ushort_t* Bn = &Bs[b ^ 1][0];

        // ph0: MFMA(tm0-3,kh0); write regP -> As[b^1]h1; issue regQ = A(t+2)h0
        PHASE({ A_WRITE(P0, P1, P2, P3, b ^ 1, 1); A_ISSUE(Q0, Q1, Q2, Q3, tt + 2, 0); },
              RD_A4(aY0, aY1, aY2, aY3, Ac, 0, 4),
              0, aX0, aX1, aX2, aX3,
              asm volatile("s_waitcnt lgkmcnt(0)" ::: "memory"))

        // ph1: MFMA(tm4-7,kh0); stage B(t+2)h0
        PHASE(STAGE2B(bPanel + (size_t)(tt + 2) * 16384, &Bs[b][0]),
              RD_A4(aX0, aX1, aX2, aX3, Ac, 1, 0); RD_B4(bY0, bY1, bY2, bY3, Bc, 1),
              4, aY0, aY1, aY2, aY3,
              {})

#undef B0_
#undef B1_
#undef B2_
#undef B3_
#define B0_ bY0
#define B1_ bY1
#define B2_ bY2
#define B3_ bY3

        // ph2: MFMA(tm0-3,kh1); write regQ -> As[b]h0; issue regP = A(t+2)h1
        PHASE({ A_WRITE(Q0, Q1, Q2, Q3, b, 0); A_ISSUE(P0, P1, P2, P3, tt + 2, 1); },
              RD_A4(aY0, aY1, aY2, aY3, Ac, 1, 4),
              0, aX0, aX1, aX2, aX3,
              asm volatile("s_waitcnt lgkmcnt(0)" ::: "memory"))

        // ph3: MFMA(tm4-7,kh1); stage B(t+2)h1
        PHASE(STAGE2B(bPanel + (size_t)(tt + 2) * 16384 + 8192, &Bs[b][8192]),
              RD_A4(aX0, aX1, aX2, aX3, An, 0, 0); RD_B4(bX0, bX1, bX2, bX3, Bn, 0),
              4, aY0, aY1, aY2, aY3,
              {})

#undef B0_
#undef B1_
#undef B2_
#undef B3_
#define B0_ bX0
#define B1_ bX1
#define B2_ bX2
#define B3_ bX3
    }

    // ---- peeled iter NT-2 (b=0): only write A(63)h1; drain B at ph3 ----
    {
        const ushort_t* Ac = &As[0][0];
        const ushort_t* Bc = &Bs[0][0];
        const ushort_t* An = &As[1][0];
        const ushort_t* Bn = &Bs[1][0];

        PHASE(A_WRITE(P0, P1, P2, P3, 1, 1),
              RD_A4(aY0, aY1, aY2, aY3, Ac, 0, 4),
              0, aX0, aX1, aX2, aX3,
              asm volatile("s_waitcnt lgkmcnt(0)" ::: "memory"))
        PHASE({},
              RD_A4(aX0, aX1, aX2, aX3, Ac, 1, 0); RD_B4(bY0, bY1, bY2, bY3, Bc, 1),
              4, aY0, aY1, aY2, aY3,
              {})
#undef B0_
#undef B1_
#undef B2_
#undef B3_
#define B0_ bY0
#define B1_ bY1
#define B2_ bY2
#define B3_ bY3
        PHASE({},
              RD_A4(aY0, aY1, aY2, aY3, Ac, 1, 4),
              0, aX0, aX1, aX2, aX3,
              {})
        PHASE({},
              RD_A4(aX0, aX1, aX2, aX3, An, 0, 0); RD_B4(bX0, bX1, bX2, bX3, Bn, 0),
              4, aY0, aY1, aY2, aY3,
              asm volatile("s_waitcnt vmcnt(0)" ::: "memory"))
#undef B0_
#undef B1_
#undef B2_
#undef B3_
#define B0_ bX0
#define B1_ bX1
#define B2_ bX2
#define B3_ bX3
    }
    // ---- peeled iter NT-1 (b=1): pure compute ----
    {
        const ushort_t* Ac = &As[1][0];
        const ushort_t* Bc = &Bs[1][0];

        PHASE({},
              RD_A4(aY0, aY1, aY2, aY3, Ac, 0, 4),
              0, aX0, aX1, aX2, aX3,
              {})
        PHASE({},
              RD_A4(aX0, aX1, aX2, aX3, Ac, 1, 0); RD_B4(bY0, bY1, bY2, bY3, Bc, 1),
              4, aY0, aY1, aY2, aY3,
              {})
#undef B0_
#undef B1_
#undef B2_
#undef B3_
#define B0_ bY0
#define B1_ bY1
#define B2_ bY2
#define B3_ bY3
        PHASE({},
              RD_A4(aY0, aY1, aY2, aY3, Ac, 1, 4),
              0, aX0, aX1, aX2, aX3,
              {})
        {
            __builtin_amdgcn_s_setprio(1);
            acc[4][0] = MFMA16(aY0, B0_, acc[4][0]);
            acc[4][1] = MFMA16(aY0, B1_, acc[4][1]);
            acc[4][2] = MFMA16(aY0, B2_, acc[4][2]);
            acc[4][3] = MFMA16(aY0, B3_, acc[4][3]);
            acc[5][0] = MFMA16(aY1, B0_, acc[5][0]);
            acc[5][1] = MFMA16(aY1, B1_, acc[5][1]);
            acc[5][2] = MFMA16(aY1, B2_, acc[5][2]);
            acc[5][3] = MFMA16(aY1, B3_, acc[5][3]);
            acc[6][0] = MFMA16(aY2, B0_, acc[6][0]);
            acc[6][1] = MFMA16(aY2, B1_, acc[6][1]);
            acc[6][2] = MFMA16(aY2, B2_, acc[6][2]);
            acc[6][3] = MFMA16(aY2, B3_, acc[6][3]);
            acc[7][0] = MFMA16(aY3, B0_, acc[7][0]);
            acc[7][1] = MFMA16(aY3, B1_, acc[7][1]);
            acc[7][2] = MFMA16(aY3, B2_, acc[7][2]);
            acc[7][3] = MFMA16(aY3, B3_, acc[7][3]);
            __builtin_amdgcn_s_setprio(0);
        }
    }

    // ---------- fused multivector normalization + store ----------
    // C/D 16x16 layout: col = lane&15, row = (lane>>4)*4 + reg.
    const int row0 = m_blk * 256 + wr * 128;
    const int col0 = n_blk * 256 + wc * 64;
#pragma unroll
    for (int tm = 0; tm < 8; ++tm) {
#pragma unroll
        for (int u = 0; u < 2; ++u) {
#pragma unroll
            for (int reg = 0; reg < 4; ++reg) {
                float v0 = acc[tm][2 * u][reg];
                float v1 = acc[tm][2 * u + 1][reg];
                float p = v0 * v0 + v1 * v1;
                p += __shfl_xor(p, 1);
                p += __shfl_xor(p, 2);
                p += __shfl_xor(p, 4);
                p += __shfl_xor(p, 8);      // stays within the 16-lane group
                const float inv = rsqrtf(p + 1e-6f);
                const int row = row0 + tm * 16 + lg * 4 + reg;
                float* orow = out + (size_t)row * 4096 + col0 + u * 32 + lm;
                orow[0]  = v0 * inv;
                orow[16] = v1 * inv;
            }
        }
    }
}

// ---------- launch ----------

extern "C" void kernel_launch(void* const* d_in, const int* in_sizes, int n_in,
                              void* d_out, int out_size, void* d_ws, size_t ws_size,
                              hipStream_t stream) {
    const float* x = (const float*)d_in[0];     // 4096 x 128 x 32 f32
    const float* w = (const float*)d_in[1];     // 128 x 128 x 32 f32
    float* out = (float*)d_out;                 // 4096 x 128 x 32 f32

    ushort_t* B_sw = (ushort_t*)d_ws;           // 32 MiB

    prepB<<<dim3(128, 64), 256, 0, stream>>>(w, B_sw);
    gemm_norm<<<dim3(256), 512, 0, stream>>>(x, B_sw, out);
}

// Round 5
// 291.123 us; speedup vs baseline: 1.0029x; 1.0029x over previous
//
#include <hip/hip_runtime.h>
#include <stdint.h>

typedef unsigned short ushort_t;
typedef __attribute__((ext_vector_type(8))) __bf16 bf16x8;
typedef __attribute__((ext_vector_type(4))) float  f32x4;

// ---------- helpers ----------

__device__ __forceinline__ unsigned int f2bf(float f) {
    unsigned int u = __float_as_uint(f);
    return (u + 0x7FFFu + ((u >> 16) & 1u)) >> 16;  // RNE
}
__device__ __forceinline__ unsigned int pk2bf(float lo, float hi) {
    return f2bf(lo) | (f2bf(hi) << 16);
}

// Cayley sign for e_a * e_b in Cl(4,1), SIG = [1,1,1,1,-1]
__device__ __forceinline__ float cayley_sign(int a, int b) {
    int s = 0;
    int aa = a >> 1;
    while (aa) { s += __popc(aa & b); aa >>= 1; }
    float sign = (s & 1) ? -1.0f : 1.0f;
    if (a & b & 16) sign = -sign;   // only SIG[4] = -1
    return sign;
}

// async global->LDS, 16 bytes per lane. LDS dest is wave-uniform base + lane*16.
__device__ __forceinline__ void async16(const ushort_t* g, const ushort_t* l) {
    const __attribute__((address_space(1))) unsigned int* gp =
        (const __attribute__((address_space(1))) unsigned int*)(uintptr_t)g;
    __attribute__((address_space(3))) unsigned int* lp =
        (__attribute__((address_space(3))) unsigned int*)(unsigned int)(uintptr_t)l;
    __builtin_amdgcn_global_load_lds(gp, lp, 16, 0, 0);
}

// ---------- B prep kernel (Cayley-folded weight, swizzled bf16 image) ----------
// B image per (panel P of 256 cols, k-tile kt of 64): 16384 bf16 laid out
// [k8(8)][col(256)][j(8)], k = k8*8+j. Each 16 KiB half = one staging half-tile.
__global__ __launch_bounds__(256) void prepB(const float* __restrict__ w,
                                             ushort_t* __restrict__ B_sw) {
    const int k_blk = blockIdx.x;            // 0..127 (32-k chunk)
    const int p_blk = blockIdx.y >> 1;       // 0..31 (128-col panel)
    const int sub   = blockIdx.y & 1;        // 0..1
    const int t = threadIdx.x;               // 0..255
    const int r  = sub * 64 + (t >> 2);      // 0..127 col within 128-panel
    const int kq = t & 3;                    // 0..3

    const int kt = k_blk >> 1;               // 64-k tile index
    const int kh = k_blk & 1;                // 32-k half

    const int n = p_blk * 128 + r;
    const int o = n >> 5;
    const int kc = n & 31;
    const float* wrow = w + (size_t)o * 4096 + (size_t)k_blk * 32;
    unsigned int pk[4];
#pragma unroll
    for (int pr = 0; pr < 4; ++pr) {
        const int i0 = kq * 8 + pr * 2, i1 = i0 + 1;
        const int j0 = i0 ^ kc, j1 = i1 ^ kc;
        float v0 = wrow[j0] * cayley_sign(i0, j0);
        float v1 = wrow[j1] * cayley_sign(i1, j1);
        pk[pr] = f2bf(v0) | (f2bf(v1) << 16);
    }
    uint4 u = {pk[0], pk[1], pk[2], pk[3]};
    const int P = n >> 8, colp = n & 255;
    *(uint4*)(B_sw + (size_t)(P * 64 + kt) * 16384 + kh * 8192 + kq * 2048 + colp * 8) = u;
}

// ---------- GEMM: 256x256, BK=64, 8 waves, fused A-staging from x ----------
// A image in LDS is BANK-SWIZZLED: element (k8, row, j) stored at row' = row ^ (k8<<1).
//  - writes (k8=lane&3, row=wave*32+(lane>>2)): each 8-lane phase covers 8 distinct
//    row-slots -> all 32 banks, conflict-free (was 4-way in round 4).
//  - reads (k8=lg, row=...+lm): permutation of a contiguous 128B run, conflict-free.
// Publish discipline: write phases (ph0/ph2) pin {2 ds_write} before {4 ds_read}
// via sched_barrier, then tail s_waitcnt lgkmcnt(4): drains the writes (cross-wave
// publish before the barrier) while leaving the prefetch reads in flight.

#define MFMA16(a, b, c) __builtin_amdgcn_mfma_f32_16x16x32_bf16(a, b, c, 0, 0, 0)

#define RD_A4(d0, d1, d2, d3, base, KH, TMB) do {                              \
        const ushort_t* _p = (base) + aOff + (KH) * 8192 + (TMB) * 128;        \
        d0 = *(const bf16x8*)(_p + 0 * 128);                                   \
        d1 = *(const bf16x8*)(_p + 1 * 128);                                   \
        d2 = *(const bf16x8*)(_p + 2 * 128);                                   \
        d3 = *(const bf16x8*)(_p + 3 * 128);                                   \
    } while (0)

#define RD_B4(d0, d1, d2, d3, base, KH) do {                                   \
        const ushort_t* _p = (base) + bOff + (KH) * 8192;                      \
        d0 = *(const bf16x8*)(_p + 0 * 128);                                   \
        d1 = *(const bf16x8*)(_p + 1 * 128);                                   \
        d2 = *(const bf16x8*)(_p + 2 * 128);                                   \
        d3 = *(const bf16x8*)(_p + 3 * 128);                                   \
    } while (0)

// load 16 f32 of A-tile T, half H (2 rows x 32 B, coalesced 128-B lines)
#define A_ISSUE(S0, S1, S2, S3, T, H) do {                                     \
        const float* _s = xbase + (size_t)(T) * 64 + (H) * 32;                 \
        S0 = *(const float4*)_s;           S1 = *(const float4*)(_s + 4);      \
        S2 = *(const float4*)(_s + 65536); S3 = *(const float4*)(_s + 65536 + 4); \
    } while (0)

// convert + ds_write into As[BUF] half H at this lane's (swizzled) image slot
#define A_WRITE(S0, S1, S2, S3, BUF, H) do {                                   \
        uint4 _p0, _p1;                                                        \
        _p0.x = pk2bf(S0.x, S0.y); _p0.y = pk2bf(S0.z, S0.w);                  \
        _p0.z = pk2bf(S1.x, S1.y); _p0.w = pk2bf(S1.z, S1.w);                  \
        _p1.x = pk2bf(S2.x, S2.y); _p1.y = pk2bf(S2.z, S2.w);                  \
        _p1.z = pk2bf(S3.x, S3.y); _p1.w = pk2bf(S3.z, S3.w);                  \
        ushort_t* _d = &As[BUF][(H) * 8192 + awOff];                           \
        *(uint4*)_d = _p0; *(uint4*)(_d + 128) = _p1;                          \
    } while (0)

// write phase: STAGE (issue globals + ds_writes) pinned BEFORE prefetch reads
#define PHASEW(STAGE_STMT, RD_STMT, TMB, A0, A1, A2, A3, TAIL)                 \
    {                                                                          \
        STAGE_STMT;                                                            \
        __builtin_amdgcn_sched_barrier(0);                                     \
        RD_STMT;                                                               \
        __builtin_amdgcn_sched_barrier(0);                                     \
        __builtin_amdgcn_s_setprio(1);                                         \
        MFMA_CLUSTER(TMB, A0, A1, A2, A3)                                      \
        __builtin_amdgcn_s_setprio(0);                                         \
        TAIL;                                                                  \
        __builtin_amdgcn_s_barrier();                                          \
    }

#define PHASE(STAGE_STMT, RD_STMT, TMB, A0, A1, A2, A3, TAIL)                  \
    {                                                                          \
        STAGE_STMT;                                                            \
        RD_STMT;                                                               \
        __builtin_amdgcn_sched_barrier(0);                                     \
        __builtin_amdgcn_s_setprio(1);                                         \
        MFMA_CLUSTER(TMB, A0, A1, A2, A3)                                      \
        __builtin_amdgcn_s_setprio(0);                                         \
        TAIL;                                                                  \
        __builtin_amdgcn_s_barrier();                                          \
    }

#define MFMA_CLUSTER(TMB, A0, A1, A2, A3)                                      \
        acc[(TMB) + 0][0] = MFMA16(A0, B0_, acc[(TMB) + 0][0]);                \
        acc[(TMB) + 0][1] = MFMA16(A0, B1_, acc[(TMB) + 0][1]);                \
        acc[(TMB) + 0][2] = MFMA16(A0, B2_, acc[(TMB) + 0][2]);                \
        acc[(TMB) + 0][3] = MFMA16(A0, B3_, acc[(TMB) + 0][3]);                \
        acc[(TMB) + 1][0] = MFMA16(A1, B0_, acc[(TMB) + 1][0]);                \
        acc[(TMB) + 1][1] = MFMA16(A1, B1_, acc[(TMB) + 1][1]);                \
        acc[(TMB) + 1][2] = MFMA16(A1, B2_, acc[(TMB) + 1][2]);                \
        acc[(TMB) + 1][3] = MFMA16(A1, B3_, acc[(TMB) + 1][3]);                \
        acc[(TMB) + 2][0] = MFMA16(A2, B0_, acc[(TMB) + 2][0]);                \
        acc[(TMB) + 2][1] = MFMA16(A2, B1_, acc[(TMB) + 2][1]);                \
        acc[(TMB) + 2][2] = MFMA16(A2, B2_, acc[(TMB) + 2][2]);                \
        acc[(TMB) + 2][3] = MFMA16(A2, B3_, acc[(TMB) + 2][3]);                \
        acc[(TMB) + 3][0] = MFMA16(A3, B0_, acc[(TMB) + 3][0]);                \
        acc[(TMB) + 3][1] = MFMA16(A3, B1_, acc[(TMB) + 3][1]);                \
        acc[(TMB) + 3][2] = MFMA16(A3, B2_, acc[(TMB) + 3][2]);                \
        acc[(TMB) + 3][3] = MFMA16(A3, B3_, acc[(TMB) + 3][3]);

__global__ __launch_bounds__(512, 2) void gemm_norm(const float* __restrict__ x,
                                                    const ushort_t* __restrict__ B_sw,
                                                    float* __restrict__ out) {
    __shared__ ushort_t As[2][16384];   // 2 x 32 KiB
    __shared__ ushort_t Bs[2][16384];   // 2 x 32 KiB  (128 KiB total, 1 block/CU)

    // XCD-aware bijective swizzle over the 256-block grid (256 % 8 == 0)
    int id = blockIdx.x;
    id = (id & 7) * 32 + (id >> 3);
    const int m_blk = id >> 4;          // 0..15
    const int n_blk = id & 15;          // 0..15

    const int t    = threadIdx.x;
    const int wave = t >> 6;            // 0..7
    const int lane = t & 63;
    const int wr = wave >> 2;           // 0..1
    const int wc = wave & 3;            // 0..3
    const int lg = lane >> 4;           // 0..3
    const int lm = lane & 15;           // 0..15

    // A reads use the swizzled row: row' = row ^ (k8<<1)  (k8 = lg)
    const int aOff = (lg * 256 + wr * 128 + (lm ^ (lg << 1))) * 8;
    const int bOff = (lg * 256 + wc * 64 + lm) * 8;       // B image linear
    // A write slot: k8 = lane&3, row = wave*32 + (lane>>2), swizzled row'
    const int awOff = (lane & 3) * 2048 +
                      ((wave * 32 + (lane >> 2)) ^ ((lane & 3) << 1)) * 8;

    // per-lane global base: row m_blk*256 + wave*32 + (lane>>2), col (lane&3)*8
    const float* xbase = x + (size_t)(m_blk * 256 + wave * 32 + (lane >> 2)) * 4096
                           + (lane & 3) * 8;
    const ushort_t* bPanel = B_sw + (size_t)n_blk * 64 * 16384;

    f32x4 acc[8][4];
#pragma unroll
    for (int i = 0; i < 8; ++i)
#pragma unroll
        for (int j = 0; j < 4; ++j)
#pragma unroll
            for (int k = 0; k < 4; ++k) acc[i][j][k] = 0.0f;

    const int so = wave * 1024 + lane * 8;
    const int sl = wave * 1024;
    auto STAGE2B = [&](const ushort_t* src, ushort_t* ldsb) {
        async16(src + so,       ldsb + sl);
        async16(src + so + 512, ldsb + sl + 512);
    };

    const int NT = 64;
    float4 P0, P1, P2, P3, Q0, Q1, Q2, Q3;

    // ---- prologue ----
    STAGE2B(bPanel + 0,             &Bs[0][0]);
    STAGE2B(bPanel + 8192,          &Bs[0][8192]);
    STAGE2B(bPanel + 16384,         &Bs[1][0]);
    STAGE2B(bPanel + 16384 + 8192,  &Bs[1][8192]);
    A_ISSUE(Q0, Q1, Q2, Q3, 0, 0);
    A_ISSUE(P0, P1, P2, P3, 0, 1);
    A_WRITE(Q0, Q1, Q2, Q3, 0, 0);
    A_WRITE(P0, P1, P2, P3, 0, 1);
    A_ISSUE(Q0, Q1, Q2, Q3, 1, 0);
    A_WRITE(Q0, Q1, Q2, Q3, 1, 0);
    A_ISSUE(P0, P1, P2, P3, 1, 1);   // A(1)h1 in flight into the loop
    asm volatile("s_waitcnt vmcnt(4) lgkmcnt(0)" ::: "memory");
    __builtin_amdgcn_s_barrier();

    bf16x8 aX0, aX1, aX2, aX3, aY0, aY1, aY2, aY3;
    bf16x8 bX0, bX1, bX2, bX3, bY0, bY1, bY2, bY3;

    RD_A4(aX0, aX1, aX2, aX3, &As[0][0], 0, 0);
    RD_B4(bX0, bX1, bX2, bX3, &Bs[0][0], 0);

#define B0_ bX0
#define B1_ bX1
#define B2_ bX2
#define B3_ bX3

#pragma unroll 2
    for (int tt = 0; tt < NT - 2; ++tt) {
        const int b = tt & 1;
        const ushort_t* Ac = &As[b][0];
        const ushort_t* Bc = &Bs[b][0];
        const ushort_t* An = &As[b ^ 1][0];
        const ushort_t* Bn = &Bs[b ^ 1][0];

        // ph0: MFMA(tm0-3,kh0); issue Q=A(t+2)h0; write P -> As[b^1]h1; lgkm(4) publish
        PHASEW({ A_ISSUE(Q0, Q1, Q2, Q3, tt + 2, 0); A_WRITE(P0, P1, P2, P3, b ^ 1, 1); },
               RD_A4(aY0, aY1, aY2, aY3, Ac, 0, 4),
               0, aX0, aX1, aX2, aX3,
               asm volatile("s_waitcnt lgkmcnt(4)" ::: "memory"))

        // ph1: MFMA(tm4-7,kh0); stage B(t+2)h0
        PHASE(STAGE2B(bPanel + (size_t)(tt + 2) * 16384, &Bs[b][0]),
              RD_A4(aX0, aX1, aX2, aX3, Ac, 1, 0); RD_B4(bY0, bY1, bY2, bY3, Bc, 1),
              4, aY0, aY1, aY2, aY3,
              {})

#undef B0_
#undef B1_
#undef B2_
#undef B3_
#define B0_ bY0
#define B1_ bY1
#define B2_ bY2
#define B3_ bY3

        // ph2: MFMA(tm0-3,kh1); issue P=A(t+2)h1; write Q -> As[b]h0; lgkm(4) publish
        PHASEW({ A_ISSUE(P0, P1, P2, P3, tt + 2, 1); A_WRITE(Q0, Q1, Q2, Q3, b, 0); },
               RD_A4(aY0, aY1, aY2, aY3, Ac, 1, 4),
               0, aX0, aX1, aX2, aX3,
               asm volatile("s_waitcnt lgkmcnt(4)" ::: "memory"))

        // ph3: MFMA(tm4-7,kh1); stage B(t+2)h1
        PHASE(STAGE2B(bPanel + (size_t)(tt + 2) * 16384 + 8192, &Bs[b][8192]),
              RD_A4(aX0, aX1, aX2, aX3, An, 0, 0); RD_B4(bX0, bX1, bX2, bX3, Bn, 0),
              4, aY0, aY1, aY2, aY3,
              {})

#undef B0_
#undef B1_
#undef B2_
#undef B3_
#define B0_ bX0
#define B1_ bX1
#define B2_ bX2
#define B3_ bX3
    }

    // ---- peeled iter NT-2 (b=0): only write A(63)h1; drain B at ph3 ----
    {
        const ushort_t* Ac = &As[0][0];
        const ushort_t* Bc = &Bs[0][0];
        const ushort_t* An = &As[1][0];
        const ushort_t* Bn = &Bs[1][0];

        PHASEW(A_WRITE(P0, P1, P2, P3, 1, 1),
               RD_A4(aY0, aY1, aY2, aY3, Ac, 0, 4),
               0, aX0, aX1, aX2, aX3,
               asm volatile("s_waitcnt lgkmcnt(4)" ::: "memory"))
        PHASE({},
              RD_A4(aX0, aX1, aX2, aX3, Ac, 1, 0); RD_B4(bY0, bY1, bY2, bY3, Bc, 1),
              4, aY0, aY1, aY2, aY3,
              {})
#undef B0_
#undef B1_
#undef B2_
#undef B3_
#define B0_ bY0
#define B1_ bY1
#define B2_ bY2
#define B3_ bY3
        PHASE({},
              RD_A4(aY0, aY1, aY2, aY3, Ac, 1, 4),
              0, aX0, aX1, aX2, aX3,
              {})
        PHASE({},
              RD_A4(aX0, aX1, aX2, aX3, An, 0, 0); RD_B4(bX0, bX1, bX2, bX3, Bn, 0),
              4, aY0, aY1, aY2, aY3,
              asm volatile("s_waitcnt vmcnt(0)" ::: "memory"))
#undef B0_
#undef B1_
#undef B2_
#undef B3_
#define B0_ bX0
#define B1_ bX1
#define B2_ bX2
#define B3_ bX3
    }
    // ---- peeled iter NT-1 (b=1): pure compute ----
    {
        const ushort_t* Ac = &As[1][0];
        const ushort_t* Bc = &Bs[1][0];

        PHASE({},
              RD_A4(aY0, aY1, aY2, aY3, Ac, 0, 4),
              0, aX0, aX1, aX2, aX3,
              {})
        PHASE({},
              RD_A4(aX0, aX1, aX2, aX3, Ac, 1, 0); RD_B4(bY0, bY1, bY2, bY3, Bc, 1),
              4, aY0, aY1, aY2, aY3,
              {})
#undef B0_
#undef B1_
#undef B2_
#undef B3_
#define B0_ bY0
#define B1_ bY1
#define B2_ bY2
#define B3_ bY3
        PHASE({},
              RD_A4(aY0, aY1, aY2, aY3, Ac, 1, 4),
              0, aX0, aX1, aX2, aX3,
              {})
        {
            __builtin_amdgcn_s_setprio(1);
            acc[4][0] = MFMA16(aY0, B0_, acc[4][0]);
            acc[4][1] = MFMA16(aY0, B1_, acc[4][1]);
            acc[4][2] = MFMA16(aY0, B2_, acc[4][2]);
            acc[4][3] = MFMA16(aY0, B3_, acc[4][3]);
            acc[5][0] = MFMA16(aY1, B0_, acc[5][0]);
            acc[5][1] = MFMA16(aY1, B1_, acc[5][1]);
            acc[5][2] = MFMA16(aY1, B2_, acc[5][2]);
            acc[5][3] = MFMA16(aY1, B3_, acc[5][3]);
            acc[6][0] = MFMA16(aY2, B0_, acc[6][0]);
            acc[6][1] = MFMA16(aY2, B1_, acc[6][1]);
            acc[6][2] = MFMA16(aY2, B2_, acc[6][2]);
            acc[6][3] = MFMA16(aY2, B3_, acc[6][3]);
            acc[7][0] = MFMA16(aY3, B0_, acc[7][0]);
            acc[7][1] = MFMA16(aY3, B1_, acc[7][1]);
            acc[7][2] = MFMA16(aY3, B2_, acc[7][2]);
            acc[7][3] = MFMA16(aY3, B3_, acc[7][3]);
            __builtin_amdgcn_s_setprio(0);
        }
    }

    // ---------- fused multivector normalization + store ----------
    // C/D 16x16 layout: col = lane&15, row = (lane>>4)*4 + reg.
    const int row0 = m_blk * 256 + wr * 128;
    const int col0 = n_blk * 256 + wc * 64;
#pragma unroll
    for (int tm = 0; tm < 8; ++tm) {
#pragma unroll
        for (int u = 0; u < 2; ++u) {
#pragma unroll
            for (int reg = 0; reg < 4; ++reg) {
                float v0 = acc[tm][2 * u][reg];
                float v1 = acc[tm][2 * u + 1][reg];
                float p = v0 * v0 + v1 * v1;
                p += __shfl_xor(p, 1);
                p += __shfl_xor(p, 2);
                p += __shfl_xor(p, 4);
                p += __shfl_xor(p, 8);      // stays within the 16-lane group
                const float inv = rsqrtf(p + 1e-6f);
                const int row = row0 + tm * 16 + lg * 4 + reg;
                float* orow = out + (size_t)row * 4096 + col0 + u * 32 + lm;
                orow[0]  = v0 * inv;
                orow[16] = v1 * inv;
            }
        }
    }
}

// ---------- launch ----------

extern "C" void kernel_launch(void* const* d_in, const int* in_sizes, int n_in,
                              void* d_out, int out_size, void* d_ws, size_t ws_size,
                              hipStream_t stream) {
    const float* x = (const float*)d_in[0];     // 4096 x 128 x 32 f32
    const float* w = (const float*)d_in[1];     // 128 x 128 x 32 f32
    float* out = (float*)d_out;                 // 4096 x 128 x 32 f32

    ushort_t* B_sw = (ushort_t*)d_ws;           // 32 MiB

    prepB<<<dim3(128, 64), 256, 0, stream>>>(w, B_sw);
    gemm_norm<<<dim3(256), 512, 0, stream>>>(x, B_sw, out);
}

// Round 6
// 244.183 us; speedup vs baseline: 1.1957x; 1.1922x over previous
//
#include <hip/hip_runtime.h>
#include <stdint.h>

typedef unsigned short ushort_t;
typedef __attribute__((ext_vector_type(8)))  __bf16 bf16x8;
typedef __attribute__((ext_vector_type(16))) float  f32x16;

// ---------- helpers ----------

__device__ __forceinline__ unsigned int f2bf(float f) {
    unsigned int u = __float_as_uint(f);
    return (u + 0x7FFFu + ((u >> 16) & 1u)) >> 16;  // RNE
}

// Cayley sign for e_a * e_b in Cl(4,1), SIG = [1,1,1,1,-1]
__device__ __forceinline__ float cayley_sign(int a, int b) {
    int s = 0;
    int aa = a >> 1;
    while (aa) { s += __popc(aa & b); aa >>= 1; }
    float sign = (s & 1) ? -1.0f : 1.0f;
    if (a & b & 16) sign = -sign;   // only SIG[4] = -1
    return sign;
}

// async global->LDS, 16 bytes per lane. LDS dest is wave-uniform base + lane*16.
__device__ __forceinline__ void async16(const ushort_t* g, const ushort_t* l) {
    const __attribute__((address_space(1))) unsigned int* gp =
        (const __attribute__((address_space(1))) unsigned int*)(uintptr_t)g;
    __attribute__((address_space(3))) unsigned int* lp =
        (__attribute__((address_space(3))) unsigned int*)(unsigned int)(uintptr_t)l;
    __builtin_amdgcn_global_load_lds(gp, lp, 16, 0, 0);
}

// ---------- merged prep kernel (round-3 version, verbatim) ----------
// Operand image per (panel P of 256 rows, k-tile kt of 64): 16384 bf16 laid out
// [k8(8)][row(256)][j(8)], k = k8*8+j. Each 16 KiB half = one staging half-tile.
__global__ __launch_bounds__(256) void prepAB(const float* __restrict__ x,
                                              const float* __restrict__ w,
                                              ushort_t* __restrict__ A_sw,
                                              ushort_t* __restrict__ B_sw) {
    const int k_blk = blockIdx.x;            // 0..127 (32-k chunk)
    const int p_blk = blockIdx.y >> 1;       // 0..31 (128-row panel)
    const int sub   = blockIdx.y & 1;        // 0..1  (64-row half)
    const int t = threadIdx.x;               // 0..255
    const int r  = sub * 64 + (t >> 2);      // 0..127 row/col within 128-panel
    const int kq = t & 3;                    // 0..3

    const int kt = k_blk >> 1;               // 64-k tile index (0..63)
    const int kh = k_blk & 1;                // which 32-k half of the tile

    if (blockIdx.z == 0) {
        // ---- A: x viewed as 4096 x 4096 row-major f32 -> bf16 swizzled ----
        const int R = p_blk * 128 + r;
        const float* src = x + (size_t)R * 4096 + (size_t)k_blk * 32 + kq * 8;
        float4 a = ((const float4*)src)[0];
        float4 b = ((const float4*)src)[1];
        uint4 pk;
        pk.x = f2bf(a.x) | (f2bf(a.y) << 16);
        pk.y = f2bf(a.z) | (f2bf(a.w) << 16);
        pk.z = f2bf(b.x) | (f2bf(b.y) << 16);
        pk.w = f2bf(b.z) | (f2bf(b.w) << 16);
        const int P = R >> 8, rowp = R & 255;
        *(uint4*)(A_sw + (size_t)(P * 64 + kt) * 16384 + kh * 8192 + kq * 2048 + rowp * 8) = pk;
    } else {
        // ---- B: Bt[n][f*32+i] = W[o, f, i^kc] * sgn(i, i^kc), n = o*32+kc ----
        const int n = p_blk * 128 + r;
        const int o = n >> 5;
        const int kc = n & 31;
        const float* wrow = w + (size_t)o * 4096 + (size_t)k_blk * 32;
        unsigned int pk[4];
#pragma unroll
        for (int pr = 0; pr < 4; ++pr) {
            const int i0 = kq * 8 + pr * 2, i1 = i0 + 1;
            const int j0 = i0 ^ kc, j1 = i1 ^ kc;
            float v0 = wrow[j0] * cayley_sign(i0, j0);
            float v1 = wrow[j1] * cayley_sign(i1, j1);
            pk[pr] = f2bf(v0) | (f2bf(v1) << 16);
        }
        uint4 u = {pk[0], pk[1], pk[2], pk[3]};
        const int P = n >> 8, colp = n & 255;
        *(uint4*)(B_sw + (size_t)(P * 64 + kt) * 16384 + kh * 8192 + kq * 2048 + colp * 8) = u;
    }
}

// ---------- GEMM: 256x256 tile, BK=64, 8 waves, 32x32x16 MFMA, 2 barriers/iter ----------
// Per wave: 128 rows x 64 cols = 4x2 tiles of 32x32; acc f32x16[4][2].
// K-tile of 64 = 4 k-steps of 16 (phases ph0..ph3). Phase p: MFMA(s=p) on one
// frag set, prefetch-read s=p+1 into the other set, stage one half-tile.
// Stages: ph0 A(t+1)h1->As[b^1], ph1 B(t+1)h1->Bs[b^1], ph2 A(t+2)h0->As[b],
//         ph3 B(t+2)h0->Bs[b].
// Barriers ONLY at ph1-end and ph3-end, each preceded by vmcnt(4):
//  - ph1-end vmcnt(4) drains A(t+1)h0/B(t+1)h0 (staged tt-1 ph2/ph3) for ph3's reads.
//  - ph3-end vmcnt(4) drains A(t+1)h1/B(t+1)h1 (staged tt ph0/ph1) for tt+1 ph1's reads.
// Stage-vs-read: every staged region's last ds_read is consumed by an MFMA at
// least one barrier before the stage issues (derivation in round-6 notes).

#define MFMA32(a, b, c) __builtin_amdgcn_mfma_f32_32x32x16_bf16(a, b, c, 0, 0, 0)

#define RD_SET(A0, A1, A2, A3, Bv0, Bv1, ABASE, BBASE, SOFS) do {              \
        const ushort_t* _pa = (ABASE) + aBase + (SOFS);                        \
        A0 = *(const bf16x8*)(_pa);                                            \
        A1 = *(const bf16x8*)(_pa + 256);                                      \
        A2 = *(const bf16x8*)(_pa + 512);                                      \
        A3 = *(const bf16x8*)(_pa + 768);                                      \
        const ushort_t* _pb = (BBASE) + bBase + (SOFS);                        \
        Bv0 = *(const bf16x8*)(_pb);                                           \
        Bv1 = *(const bf16x8*)(_pb + 256);                                     \
    } while (0)

#define MFMA_SET(A0, A1, A2, A3, Bv0, Bv1)                                     \
        __builtin_amdgcn_s_setprio(1);                                         \
        acc[0][0] = MFMA32(A0, Bv0, acc[0][0]);                                \
        acc[0][1] = MFMA32(A0, Bv1, acc[0][1]);                                \
        acc[1][0] = MFMA32(A1, Bv0, acc[1][0]);                                \
        acc[1][1] = MFMA32(A1, Bv1, acc[1][1]);                                \
        acc[2][0] = MFMA32(A2, Bv0, acc[2][0]);                                \
        acc[2][1] = MFMA32(A2, Bv1, acc[2][1]);                                \
        acc[3][0] = MFMA32(A3, Bv0, acc[3][0]);                                \
        acc[3][1] = MFMA32(A3, Bv1, acc[3][1]);                                \
        __builtin_amdgcn_s_setprio(0);

#define SBAR0() __builtin_amdgcn_sched_barrier(0)

__global__ __launch_bounds__(512, 2) void gemm_norm(const ushort_t* __restrict__ A_sw,
                                                    const ushort_t* __restrict__ B_sw,
                                                    float* __restrict__ out) {
    __shared__ ushort_t As[2][16384];   // 2 x 32 KiB
    __shared__ ushort_t Bs[2][16384];   // 2 x 32 KiB  (128 KiB total, 1 block/CU)

    // XCD-aware bijective swizzle over the 256-block grid (256 % 8 == 0)
    int id = blockIdx.x;
    id = (id & 7) * 32 + (id >> 3);
    const int m_blk = id >> 4;          // 0..15
    const int n_blk = id & 15;          // 0..15

    const int t    = threadIdx.x;
    const int wave = t >> 6;            // 0..7
    const int lane = t & 63;
    const int wr = wave >> 2;           // 0..1  (row half of 256)
    const int wc = wave & 3;            // 0..3  (64-col slice)
    const int half = lane >> 5;         // 0..1  (k-half within 16-step)
    const int l32  = lane & 31;         // 0..31 (m/n within 32-tile)

    // frag base offsets into the [k8(8)][row(256)][j(8)] image (elements)
    const int aBase = half * 2048 + (wr * 128 + l32) * 8;
    const int bBase = half * 2048 + (wc * 64 + l32) * 8;

    const ushort_t* aPanel = A_sw + (size_t)m_blk * 64 * 16384;
    const ushort_t* bPanel = B_sw + (size_t)n_blk * 64 * 16384;

    f32x16 acc[4][2];
#pragma unroll
    for (int i = 0; i < 4; ++i)
#pragma unroll
        for (int j = 0; j < 2; ++j)
#pragma unroll
            for (int k = 0; k < 16; ++k) acc[i][j][k] = 0.0f;

    const int so = wave * 1024 + lane * 8;  // per-lane global elem offset of stage slice
    const int sl = wave * 1024;             // wave-uniform LDS elem offset

    auto STAGE2 = [&](const ushort_t* src, ushort_t* ldsb) {
        async16(src + so,       ldsb + sl);
        async16(src + so + 512, ldsb + sl + 512);
    };

    const int NT = 64;

    // ---- prologue: A0h0,B0h0,A0h1,B0h1 landed; A1h0,B1h0 in flight ----
    STAGE2(aPanel + 0,            &As[0][0]);
    STAGE2(bPanel + 0,            &Bs[0][0]);
    STAGE2(aPanel + 8192,         &As[0][8192]);
    STAGE2(bPanel + 8192,         &Bs[0][8192]);
    STAGE2(aPanel + 16384,        &As[1][0]);
    STAGE2(bPanel + 16384,        &Bs[1][0]);
    asm volatile("s_waitcnt vmcnt(4)" ::: "memory");
    __builtin_amdgcn_s_barrier();

    // frag register sets (ping-pong): X computes even k-steps, Y odd.
    bf16x8 xa0, xa1, xa2, xa3, xb0, xb1;
    bf16x8 ya0, ya1, ya2, ya3, yb0, yb1;

    RD_SET(xa0, xa1, xa2, xa3, xb0, xb1, &As[0][0], &Bs[0][0], 0);   // s0

#pragma unroll 2
    for (int tt = 0; tt < NT - 2; ++tt) {
        const int b = tt & 1;
        const ushort_t* Ac = &As[b][0];
        const ushort_t* Bc = &Bs[b][0];
        ushort_t* An = &As[b ^ 1][0];
        ushort_t* Bn = &Bs[b ^ 1][0];

        // ph0: MFMA s0 (X); read Y<-s1; stage A(t+1)h1 -> As[b^1]h1
        STAGE2(aPanel + (size_t)(tt + 1) * 16384 + 8192, An + 8192);
        RD_SET(ya0, ya1, ya2, ya3, yb0, yb1, Ac, Bc, 4096);
        SBAR0();
        MFMA_SET(xa0, xa1, xa2, xa3, xb0, xb1)

        // ph1: MFMA s1 (Y); read X<-s2; stage B(t+1)h1 -> Bs[b^1]h1
        STAGE2(bPanel + (size_t)(tt + 1) * 16384 + 8192, Bn + 8192);
        RD_SET(xa0, xa1, xa2, xa3, xb0, xb1, Ac, Bc, 8192);
        SBAR0();
        MFMA_SET(ya0, ya1, ya2, ya3, yb0, yb1)
        asm volatile("s_waitcnt vmcnt(4)" ::: "memory");
        __builtin_amdgcn_s_barrier();

        // ph2: MFMA s2 (X); read Y<-s3; stage A(t+2)h0 -> As[b]h0
        STAGE2(aPanel + (size_t)(tt + 2) * 16384, &As[b][0]);
        RD_SET(ya0, ya1, ya2, ya3, yb0, yb1, Ac, Bc, 12288);
        SBAR0();
        MFMA_SET(xa0, xa1, xa2, xa3, xb0, xb1)

        // ph3: MFMA s3 (Y); read X<-s0 of tile t+1; stage B(t+2)h0 -> Bs[b]h0
        STAGE2(bPanel + (size_t)(tt + 2) * 16384, &Bs[b][0]);
        RD_SET(xa0, xa1, xa2, xa3, xb0, xb1, An, Bn, 0);
        SBAR0();
        MFMA_SET(ya0, ya1, ya2, ya3, yb0, yb1)
        asm volatile("s_waitcnt vmcnt(4)" ::: "memory");
        __builtin_amdgcn_s_barrier();
    }

    // ---- peeled iter NT-2 (b=0): stage only A(63)h1 / B(63)h1 ----
    {
        const ushort_t* Ac = &As[0][0];
        const ushort_t* Bc = &Bs[0][0];
        ushort_t* An = &As[1][0];
        ushort_t* Bn = &Bs[1][0];

        STAGE2(aPanel + (size_t)(NT - 1) * 16384 + 8192, An + 8192);
        RD_SET(ya0, ya1, ya2, ya3, yb0, yb1, Ac, Bc, 4096);
        SBAR0();
        MFMA_SET(xa0, xa1, xa2, xa3, xb0, xb1)

        STAGE2(bPanel + (size_t)(NT - 1) * 16384 + 8192, Bn + 8192);
        RD_SET(xa0, xa1, xa2, xa3, xb0, xb1, Ac, Bc, 8192);
        SBAR0();
        MFMA_SET(ya0, ya1, ya2, ya3, yb0, yb1)
        asm volatile("s_waitcnt vmcnt(4)" ::: "memory");   // drain A63h0,B63h0
        __builtin_amdgcn_s_barrier();

        RD_SET(ya0, ya1, ya2, ya3, yb0, yb1, Ac, Bc, 12288);
        SBAR0();
        MFMA_SET(xa0, xa1, xa2, xa3, xb0, xb1)

        RD_SET(xa0, xa1, xa2, xa3, xb0, xb1, An, Bn, 0);
        SBAR0();
        MFMA_SET(ya0, ya1, ya2, ya3, yb0, yb1)
        asm volatile("s_waitcnt vmcnt(0)" ::: "memory");   // drain A63h1,B63h1
        __builtin_amdgcn_s_barrier();
    }
    // ---- peeled iter NT-1 (b=1): pure compute ----
    {
        const ushort_t* Ac = &As[1][0];
        const ushort_t* Bc = &Bs[1][0];

        RD_SET(ya0, ya1, ya2, ya3, yb0, yb1, Ac, Bc, 4096);
        SBAR0();
        MFMA_SET(xa0, xa1, xa2, xa3, xb0, xb1)

        RD_SET(xa0, xa1, xa2, xa3, xb0, xb1, Ac, Bc, 8192);
        SBAR0();
        MFMA_SET(ya0, ya1, ya2, ya3, yb0, yb1)

        RD_SET(ya0, ya1, ya2, ya3, yb0, yb1, Ac, Bc, 12288);
        SBAR0();
        MFMA_SET(xa0, xa1, xa2, xa3, xb0, xb1)

        SBAR0();
        MFMA_SET(ya0, ya1, ya2, ya3, yb0, yb1)
    }

    // ---------- fused multivector normalization + store ----------
    // 32x32 C/D layout (m74/m101, round-0 verified): col = lane&31,
    // row = (reg&3) + 8*(reg>>2) + 4*(lane>>5). Each 32-col tile = one
    // output multivector group; reduce across the 32-lane half.
    const int row0 = m_blk * 256 + wr * 128;
    const int col0 = n_blk * 256 + wc * 64;
#pragma unroll
    for (int tm = 0; tm < 4; ++tm) {
#pragma unroll
        for (int tn = 0; tn < 2; ++tn) {
            const int cbase = col0 + tn * 32 + l32;
#pragma unroll
            for (int reg = 0; reg < 16; ++reg) {
                float v = acc[tm][tn][reg];
                float p = v * v;
                p += __shfl_xor(p, 1);
                p += __shfl_xor(p, 2);
                p += __shfl_xor(p, 4);
                p += __shfl_xor(p, 8);
                p += __shfl_xor(p, 16);   // stays within the 32-lane half
                const float inv = rsqrtf(p + 1e-6f);
                const int row = row0 + tm * 32 + (reg & 3) + 8 * (reg >> 2) + 4 * half;
                out[(size_t)row * 4096 + cbase] = v * inv;
            }
        }
    }
}

// ---------- launch ----------

extern "C" void kernel_launch(void* const* d_in, const int* in_sizes, int n_in,
                              void* d_out, int out_size, void* d_ws, size_t ws_size,
                              hipStream_t stream) {
    const float* x = (const float*)d_in[0];     // 4096 x 128 x 32 f32
    const float* w = (const float*)d_in[1];     // 128 x 128 x 32 f32
    float* out = (float*)d_out;                 // 4096 x 128 x 32 f32

    ushort_t* A_sw = (ushort_t*)d_ws;                       // 32 MiB
    ushort_t* B_sw = A_sw + (size_t)4096 * 4096;            // 32 MiB

    prepAB<<<dim3(128, 64, 2), 256, 0, stream>>>(x, w, A_sw, B_sw);
    gemm_norm<<<dim3(32 * 8), 512, 0, stream>>>(A_sw, B_sw, out);
}